// Round 2
// baseline (562.840 us; speedup 1.0000x reference)
//
#include <hip/hip_runtime.h>

typedef __attribute__((ext_vector_type(4))) float f32x4;
typedef __attribute__((ext_vector_type(8))) short s16x8;
typedef __attribute__((ext_vector_type(8))) unsigned short u16x8;

#define W_DIM   512
#define CHANNELS 1024
#define SPATIAL 4096   /* 64*64 */
#define NB      16

__device__ inline unsigned short f2bf(float x){
  unsigned int u = __float_as_uint(x);
  u += 0x7fffu + ((u >> 16) & 1u);   // round-to-nearest-even
  return (unsigned short)(u >> 16);
}

// sin/cos of 2*pi*x: v_sin_f32/v_cos_f32 take revolutions; fract for domain.
__device__ inline float sin2pi(float x){
  return __builtin_amdgcn_sinf(__builtin_amdgcn_fractf(x));
}
__device__ inline float cos2pi(float x){
  return __builtin_amdgcn_cosf(__builtin_amdgcn_fractf(x));
}

__device__ inline void async_load16(const unsigned short* g, unsigned short* l){
  __builtin_amdgcn_global_load_lds(
      (const __attribute__((address_space(1))) void*)g,
      (__attribute__((address_space(3))) void*)l, 16, 0, 0);
}

// ---------------------------------------------------------------- setup ----
__global__ void sy_setup(const float* __restrict__ w, const float* __restrict__ freqs,
                         const float* __restrict__ phases, const float* __restrict__ affine_w,
                         const float* __restrict__ affine_b, float4* __restrict__ params){
  int b = blockIdx.x;
  int t = threadIdx.x;
  float p0=0.f, p1=0.f, p2=0.f, p3=0.f;
  #pragma unroll
  for (int it = 0; it < 2; ++it){
    int i = t + it*256;
    float wv = w[b*W_DIM + i];
    p0 += wv * affine_w[0*W_DIM + i];
    p1 += wv * affine_w[1*W_DIM + i];
    p2 += wv * affine_w[2*W_DIM + i];
    p3 += wv * affine_w[3*W_DIM + i];
  }
  #pragma unroll
  for (int off = 32; off >= 1; off >>= 1){
    p0 += __shfl_down(p0, off);
    p1 += __shfl_down(p1, off);
    p2 += __shfl_down(p2, off);
    p3 += __shfl_down(p3, off);
  }
  __shared__ float red[4][4];
  __shared__ float sc[4];
  int wave = t >> 6, lane = t & 63;
  if (lane == 0){ red[wave][0]=p0; red[wave][1]=p1; red[wave][2]=p2; red[wave][3]=p3; }
  __syncthreads();
  if (t == 0){
    const float inv_sq = 0.04419417382415922f; // 1/sqrt(512)
    float tv[4];
    #pragma unroll
    for (int j=0;j<4;++j){
      float s = red[0][j]+red[1][j]+red[2][j]+red[3][j];
      tv[j] = s * inv_sq + affine_b[j];
    }
    float n  = sqrtf(tv[0]*tv[0] + tv[1]*tv[1]);
    float iv = 1.0f / n;
    float c = tv[0]*iv, s = tv[1]*iv;
    float t2 = tv[2]*iv, t3 = tv[3]*iv;
    float tcx = -(c*t2 - s*t3);
    float tcy = -(s*t2 + c*t3);
    sc[0]=c; sc[1]=s; sc[2]=tcx; sc[3]=tcy;
  }
  __syncthreads();
  float c = sc[0], s = sc[1], tcx = sc[2], tcy = sc[3];
  #pragma unroll
  for (int j = 0; j < 4; ++j){
    int ci = t + j*256;
    float f0x = freqs[ci*2], f0y = freqs[ci*2+1];
    float fx =  f0x*c + f0y*s;
    float fy = -f0x*s + f0y*c;
    float ph = phases[ci] + f0x*tcx + f0y*tcy;
    float r  = sqrtf(fx*fx + fy*fy);
    float amp = 1.0f - (r - 2.0f) * (1.0f/30.0f);
    amp = fminf(fmaxf(amp, 0.0f), 1.0f);
    float4 P; P.x=fx; P.y=fy; P.z=ph; P.w=amp;
    params[b*CHANNELS + ci] = P;
  }
}

// ------------------------------------------------------ weight -> bf16 -----
__global__ void sy_cvtw(const float* __restrict__ wt, unsigned short* __restrict__ Wbf){
  int i = (blockIdx.x*256 + threadIdx.x)*4;
  float4 v = *(const float4*)(wt + i);
  ushort4 o;
  o.x = f2bf(v.x*0.03125f); o.y = f2bf(v.y*0.03125f);
  o.z = f2bf(v.z*0.03125f); o.w = f2bf(v.w*0.03125f);
  *(ushort4*)(Wbf + i) = o;
}

// ---------------------------------------------------------------- gen S ----
// Separable: sin(2pi(U+V)) = sinU*(cosV*amp) + cosU*(sinV*amp), U=u*fx,
// V=v*fy+ph. u advances by 1/64 -> (sinU,cosU) rotation recurrence (2 FMA
// per component). Thread: 8 channels x 16 consecutive m (fixed h).
__global__ void sy_genS(const float4* __restrict__ params, unsigned short* __restrict__ Sbf,
                        int b0){
  int blk = blockIdx.x;
  int bb  = blk >> 7;
  int b   = b0 + bb;
  int m0  = (blk & 127) * 32;
  int t   = threadIdx.x;
  int c0  = (t & 127) * 8;
  int mh  = t >> 7;              // 0 or 1: which 16-m half
  int h   = m0 >> 6;
  int w0  = (m0 + mh*16) & 63;
  float v  = (h  + 0.5f) * (1.0f/64.0f) - 0.5f;
  float u0 = (w0 + 0.5f) * (1.0f/64.0f) - 0.5f;

  float sU[8], cU[8], sV[8], cV[8], sD[8], cD[8];
  #pragma unroll
  for (int j = 0; j < 8; ++j){
    float4 P = params[b*CHANNELS + c0 + j];
    float V = v*P.y + P.z;
    sV[j] = sin2pi(V) * P.w;
    cV[j] = cos2pi(V) * P.w;
    float U = u0*P.x;
    sU[j] = sin2pi(U);
    cU[j] = cos2pi(U);
    float D = P.x * (1.0f/64.0f);
    sD[j] = sin2pi(D);
    cD[j] = cos2pi(D);
  }

  unsigned short* dst = Sbf + ((size_t)bb * SPATIAL + m0 + mh*16) * CHANNELS + c0;
  for (int im = 0; im < 16; ++im){
    u16x8 o;
    #pragma unroll
    for (int j = 0; j < 8; ++j){
      float val = sU[j]*cV[j] + cU[j]*sV[j];
      o[j] = f2bf(val);
      float ns = sU[j]*cD[j] + cU[j]*sD[j];
      float nc = cU[j]*cD[j] - sU[j]*sD[j];
      sU[j] = ns; cU[j] = nc;
    }
    *(u16x8*)(dst + (size_t)im * CHANNELS) = o;
  }
}

// ----------------------------------------------------------------- GEMM ----
// out[b][row=k][col=m] = sum_c Wbf[row][c] * Sbf[b][col][c].
// 128x128 tile, BK=32, 4 waves in 2x2, each wave 4x4 mfma_f32_16x16x32_bf16.
// LDS tile layout is [rowblock16][kchunk(4x16B)][row16] so ds_read_b128
// fragment reads are bank-conflict-free (8 consecutive lanes sweep all 32
// banks). global_load_lds dest stays contiguous (lane*16B); only the global
// source permutation changes.
__global__ __launch_bounds__(256) void sy_gemm(const unsigned short* __restrict__ Wbf,
                                               const unsigned short* __restrict__ Sbf,
                                               float* __restrict__ out, int b0){
  __shared__ unsigned short lA[128*32];
  __shared__ unsigned short lB[128*32];
  const int nt = blockIdx.x, mt = blockIdx.y, bb = blockIdx.z;
  const int b = b0 + bb;
  const int tid  = threadIdx.x;
  const int lane = tid & 63, wave = tid >> 6;
  const int wm = wave & 1, wn = wave >> 1;
  const int Mbase = mt * 128, Nbase = nt * 128;

  // staging: 512 16B-chunks per tile; thread does chunks q0 and q0+64.
  // chunk q -> rowblock rb=q>>6, kchunk kc=(q>>4)&3, row16 r=q&15;
  // global row = rb*16+r, k-offset = kc*8.
  const int q0 = wave*128 + lane, q1 = q0 + 64;
  const int r0 = (q0>>6)*16 + (q0&15), k0 = ((q0>>4)&3)*8;
  const int r1 = (q1>>6)*16 + (q1&15), k1 = ((q1>>4)&3)*8;
  const unsigned short* gA0 = Wbf + (size_t)(Mbase + r0)*CHANNELS + k0;
  const unsigned short* gA1 = Wbf + (size_t)(Mbase + r1)*CHANNELS + k1;
  const unsigned short* gB0 = Sbf + ((size_t)bb*SPATIAL + Nbase + r0)*CHANNELS + k0;
  const unsigned short* gB1 = Sbf + ((size_t)bb*SPATIAL + Nbase + r1)*CHANNELS + k1;
  unsigned short* lA0 = lA + q0*8;
  unsigned short* lA1 = lA + q1*8;
  unsigned short* lB0 = lB + q0*8;
  unsigned short* lB1 = lB + q1*8;

  f32x4 acc[4][4];
  #pragma unroll
  for (int i=0;i<4;++i)
    #pragma unroll
    for (int j=0;j<4;++j){
      f32x4 z = {0.f,0.f,0.f,0.f};
      acc[i][j] = z;
    }

  // fragment read base (shorts): physical addr of (row, kc) =
  // (row>>4)*512 + kc*128 + (row&15)*8
  const int rA = wm*2048 + (lane>>4)*128 + (lane&15)*8;  // + i*512 per subtile
  const int rB = wn*2048 + (lane>>4)*128 + (lane&15)*8;

  for (int kt = 0; kt < 32; ++kt){
    const int ko = kt * 32;
    async_load16(gA0 + ko, lA0);
    async_load16(gA1 + ko, lA1);
    async_load16(gB0 + ko, lB0);
    async_load16(gB1 + ko, lB1);
    __syncthreads();                                 // drains vmcnt before barrier
    s16x8 af[4], bv[4];
    #pragma unroll
    for (int i=0;i<4;++i) af[i] = *(const s16x8*)&lA[rA + i*512];
    #pragma unroll
    for (int j=0;j<4;++j) bv[j] = *(const s16x8*)&lB[rB + j*512];
    #pragma unroll
    for (int i=0;i<4;++i)
      #pragma unroll
      for (int j=0;j<4;++j)
        acc[i][j] = __builtin_amdgcn_mfma_f32_16x16x32_bf16(af[i], bv[j], acc[i][j], 0, 0, 0);
    __syncthreads();
  }

  // C/D layout: col = lane&15, row = (lane>>4)*4 + reg
  float* outb = out + (size_t)b * CHANNELS * SPATIAL;
  const int col  = Nbase + wn*64 + (lane & 15);
  const int row0 = Mbase + wm*64 + ((lane >> 4) << 2);
  #pragma unroll
  for (int i=0;i<4;++i)
    #pragma unroll
    for (int j=0;j<4;++j)
      #pragma unroll
      for (int r=0;r<4;++r)
        outb[(size_t)(row0 + i*16 + r) * SPATIAL + (col + j*16)] = acc[i][j][r];
}

// ---------------------------------------------- emergency small-ws path ----
__global__ void sy_fallback(const float* __restrict__ weight, const float4* __restrict__ params,
                            float* __restrict__ out){
  extern __shared__ float S[];   // 32*1024 floats = 128 KB
  int b  = blockIdx.x >> 7;
  int m0 = (blockIdx.x & 127) * 32;
  int t  = threadIdx.x;
  {
    int c0 = t*4;
    float4 P0 = params[b*CHANNELS+c0+0], P1 = params[b*CHANNELS+c0+1];
    float4 P2 = params[b*CHANNELS+c0+2], P3 = params[b*CHANNELS+c0+3];
    int h = m0 >> 6;
    float v = (h + 0.5f)*(1.0f/64.0f) - 0.5f;
    float a0 = v*P0.y+P0.z, a1 = v*P1.y+P1.z, a2 = v*P2.y+P2.z, a3 = v*P3.y+P3.z;
    for (int im = 0; im < 32; ++im){
      int wv = (m0+im) & 63;
      float u = (wv+0.5f)*(1.0f/64.0f) - 0.5f;
      float* row = S + im*CHANNELS + c0;
      row[0] = sin2pi(u*P0.x+a0)*P0.w;
      row[1] = sin2pi(u*P1.x+a1)*P1.w;
      row[2] = sin2pi(u*P2.x+a2)*P2.w;
      row[3] = sin2pi(u*P3.x+a3)*P3.w;
    }
  }
  __syncthreads();
  for (int oi = t; oi < 32*1024; oi += 256){
    int k = oi >> 5, im = oi & 31;
    const float4* wr = (const float4*)(weight + (size_t)k*CHANNELS);
    const float4* sr = (const float4*)(S + im*CHANNELS);
    float sum = 0.f;
    for (int c4 = 0; c4 < CHANNELS/4; ++c4){
      float4 a = wr[c4], s4 = sr[c4];
      sum += a.x*s4.x + a.y*s4.y + a.z*s4.z + a.w*s4.w;
    }
    out[((size_t)b*CHANNELS + k)*SPATIAL + m0 + im] = sum * 0.03125f;
  }
}

extern "C" void kernel_launch(void* const* d_in, const int* in_sizes, int n_in,
                              void* d_out, int out_size, void* d_ws, size_t ws_size,
                              hipStream_t stream){
  const float* w        = (const float*)d_in[0];
  const float* freqs    = (const float*)d_in[1];
  const float* phases   = (const float*)d_in[2];
  const float* weight   = (const float*)d_in[3];
  const float* affine_w = (const float*)d_in[4];
  const float* affine_b = (const float*)d_in[5];
  float* out = (float*)d_out;

  char* ws = (char*)d_ws;
  float4* params = (float4*)ws;                       // 256 KB
  const size_t off_w = 262144;                        // Wbf: 2 MiB
  const size_t off_s = off_w + 2097152;               // Sbf: up to 128 MiB
  unsigned short* Wbf = (unsigned short*)(ws + off_w);
  unsigned short* Sbf = (unsigned short*)(ws + off_s);
  const size_t per_batch = (size_t)SPATIAL * CHANNELS * 2;  // 8 MiB

  sy_setup<<<NB, 256, 0, stream>>>(w, freqs, phases, affine_w, affine_b, params);

  int G = 0;
  if (ws_size >= off_s + per_batch){
    size_t avail = (ws_size - off_s) / per_batch;
    G = avail >= (size_t)NB ? NB : (int)avail;
  }
  if (G == 0){
    sy_fallback<<<NB*128, 256, 32*1024*4, stream>>>(weight, params, out);
    return;
  }
  sy_cvtw<<<1024, 256, 0, stream>>>(weight, Wbf);
  for (int b0 = 0; b0 < NB; b0 += G){
    int g = (NB - b0) < G ? (NB - b0) : G;
    sy_genS<<<g*128, 256, 0, stream>>>(params, Sbf, b0);
    dim3 grid(32, 8, g);
    sy_gemm<<<grid, 256, 0, stream>>>(Wbf, Sbf, out, b0);
  }
}

// Round 3
// 474.297 us; speedup vs baseline: 1.1867x; 1.1867x over previous
//
#include <hip/hip_runtime.h>

typedef __attribute__((ext_vector_type(4))) float f32x4;
typedef __attribute__((ext_vector_type(8))) short s16x8;
typedef __attribute__((ext_vector_type(8))) unsigned short u16x8;

#define W_DIM   512
#define CHANNELS 1024
#define SPATIAL 4096   /* 64*64 */
#define NB      16

__device__ inline unsigned short f2bf(float x){
  unsigned int u = __float_as_uint(x);
  u += 0x7fffu + ((u >> 16) & 1u);   // round-to-nearest-even
  return (unsigned short)(u >> 16);
}

// sin/cos of 2*pi*x: v_sin_f32/v_cos_f32 take revolutions; fract for domain.
__device__ inline float sin2pi(float x){
  return __builtin_amdgcn_sinf(__builtin_amdgcn_fractf(x));
}
__device__ inline float cos2pi(float x){
  return __builtin_amdgcn_cosf(__builtin_amdgcn_fractf(x));
}

__device__ inline void async_load16(const unsigned short* g, unsigned short* l){
  __builtin_amdgcn_global_load_lds(
      (const __attribute__((address_space(1))) void*)g,
      (__attribute__((address_space(3))) void*)l, 16, 0, 0);
}

// ---------------------------------------------------------------- setup ----
__global__ void sy_setup(const float* __restrict__ w, const float* __restrict__ freqs,
                         const float* __restrict__ phases, const float* __restrict__ affine_w,
                         const float* __restrict__ affine_b, float4* __restrict__ params){
  int b = blockIdx.x;
  int t = threadIdx.x;
  float p0=0.f, p1=0.f, p2=0.f, p3=0.f;
  #pragma unroll
  for (int it = 0; it < 2; ++it){
    int i = t + it*256;
    float wv = w[b*W_DIM + i];
    p0 += wv * affine_w[0*W_DIM + i];
    p1 += wv * affine_w[1*W_DIM + i];
    p2 += wv * affine_w[2*W_DIM + i];
    p3 += wv * affine_w[3*W_DIM + i];
  }
  #pragma unroll
  for (int off = 32; off >= 1; off >>= 1){
    p0 += __shfl_down(p0, off);
    p1 += __shfl_down(p1, off);
    p2 += __shfl_down(p2, off);
    p3 += __shfl_down(p3, off);
  }
  __shared__ float red[4][4];
  __shared__ float sc[4];
  int wave = t >> 6, lane = t & 63;
  if (lane == 0){ red[wave][0]=p0; red[wave][1]=p1; red[wave][2]=p2; red[wave][3]=p3; }
  __syncthreads();
  if (t == 0){
    const float inv_sq = 0.04419417382415922f; // 1/sqrt(512)
    float tv[4];
    #pragma unroll
    for (int j=0;j<4;++j){
      float s = red[0][j]+red[1][j]+red[2][j]+red[3][j];
      tv[j] = s * inv_sq + affine_b[j];
    }
    float n  = sqrtf(tv[0]*tv[0] + tv[1]*tv[1]);
    float iv = 1.0f / n;
    float c = tv[0]*iv, s = tv[1]*iv;
    float t2 = tv[2]*iv, t3 = tv[3]*iv;
    float tcx = -(c*t2 - s*t3);
    float tcy = -(s*t2 + c*t3);
    sc[0]=c; sc[1]=s; sc[2]=tcx; sc[3]=tcy;
  }
  __syncthreads();
  float c = sc[0], s = sc[1], tcx = sc[2], tcy = sc[3];
  #pragma unroll
  for (int j = 0; j < 4; ++j){
    int ci = t + j*256;
    float f0x = freqs[ci*2], f0y = freqs[ci*2+1];
    float fx =  f0x*c + f0y*s;
    float fy = -f0x*s + f0y*c;
    float ph = phases[ci] + f0x*tcx + f0y*tcy;
    float r  = sqrtf(fx*fx + fy*fy);
    float amp = 1.0f - (r - 2.0f) * (1.0f/30.0f);
    amp = fminf(fmaxf(amp, 0.0f), 1.0f);
    float4 P; P.x=fx; P.y=fy; P.z=ph; P.w=amp;
    params[b*CHANNELS + ci] = P;
  }
}

// ------------------------------------------------------ weight -> bf16 -----
__global__ void sy_cvtw(const float* __restrict__ wt, unsigned short* __restrict__ Wbf){
  int i = (blockIdx.x*256 + threadIdx.x)*4;
  float4 v = *(const float4*)(wt + i);
  ushort4 o;
  o.x = f2bf(v.x*0.03125f); o.y = f2bf(v.y*0.03125f);
  o.z = f2bf(v.z*0.03125f); o.w = f2bf(v.w*0.03125f);
  *(ushort4*)(Wbf + i) = o;
}

// ---------------------------------------------------------------- gen S ----
// Separable: sin(2pi(U+V)) = sinU*(cosV*amp) + cosU*(sinV*amp), U=u*fx,
// V=v*fy+ph; (sinU,cosU) advanced by fixed rotation per u step.
__global__ void sy_genS(const float4* __restrict__ params, unsigned short* __restrict__ Sbf,
                        int b0){
  int blk = blockIdx.x;
  int bb  = blk >> 7;
  int b   = b0 + bb;
  int m0  = (blk & 127) * 32;
  int t   = threadIdx.x;
  int c0  = (t & 127) * 8;
  int mh  = t >> 7;              // 0 or 1: which 16-m half
  int h   = m0 >> 6;
  int w0  = (m0 + mh*16) & 63;
  float v  = (h  + 0.5f) * (1.0f/64.0f) - 0.5f;
  float u0 = (w0 + 0.5f) * (1.0f/64.0f) - 0.5f;

  float sU[8], cU[8], sV[8], cV[8], sD[8], cD[8];
  #pragma unroll
  for (int j = 0; j < 8; ++j){
    float4 P = params[b*CHANNELS + c0 + j];
    float V = v*P.y + P.z;
    sV[j] = sin2pi(V) * P.w;
    cV[j] = cos2pi(V) * P.w;
    float U = u0*P.x;
    sU[j] = sin2pi(U);
    cU[j] = cos2pi(U);
    float D = P.x * (1.0f/64.0f);
    sD[j] = sin2pi(D);
    cD[j] = cos2pi(D);
  }

  unsigned short* dst = Sbf + ((size_t)bb * SPATIAL + m0 + mh*16) * CHANNELS + c0;
  for (int im = 0; im < 16; ++im){
    u16x8 o;
    #pragma unroll
    for (int j = 0; j < 8; ++j){
      float val = sU[j]*cV[j] + cU[j]*sV[j];
      o[j] = f2bf(val);
      float ns = sU[j]*cD[j] + cU[j]*sD[j];
      float nc = cU[j]*cD[j] - sU[j]*sD[j];
      sU[j] = ns; cU[j] = nc;
    }
    *(u16x8*)(dst + (size_t)im * CHANNELS) = o;
  }
}

// ----------------------------------------------------------------- GEMM ----
// out[b][row=k][col=m] = sum_c Wbf[row][c] * Sbf[b][col][c].
// 128x128 tile, BK=64, 4 waves 2x2, each wave 4x4 mfma_f32_16x16x32_bf16
// over 2 k-steps per staged tile.
// LDS: chunk(16B) for (row, kc) lives at chunk index row*8 + (kc ^ (row&7)).
// XOR permutes within a row's 128B segment -> global staging still reads
// whole contiguous 128B row segments (8 lanes each); fragment ds_read_b128:
// 8 consecutive lanes sweep all 32 banks once (2-way alias at lanes+8 is
// free per m136).
__global__ __launch_bounds__(256) void sy_gemm(const unsigned short* __restrict__ Wbf,
                                               const unsigned short* __restrict__ Sbf,
                                               float* __restrict__ out, int b0){
  __shared__ unsigned short lA[128*64];   // 16 KB
  __shared__ unsigned short lB[128*64];   // 16 KB
  const int nt = blockIdx.x, mt = blockIdx.y, bb = blockIdx.z;
  const int b = b0 + bb;
  const int tid  = threadIdx.x;
  const int lane = tid & 63, wave = tid >> 6;
  const int wm = wave & 1, wn = wave >> 1;
  const int Mbase = mt * 128, Nbase = nt * 128;

  // staging: 1024 chunks per tile; inst j covers chunks (wave*4+j)*64+lane.
  // chunk p holds global (row = p>>3, kc = (p&7) ^ (row&7)).
  int voff[4];   // global short-offset (row*1024 + kc*8), per inst
  int loff[4];   // lds short-offset p*8
  #pragma unroll
  for (int j = 0; j < 4; ++j){
    int p   = (wave*4 + j)*64 + lane;
    int row = p >> 3;
    int kc  = (p & 7) ^ (row & 7);
    voff[j] = row*CHANNELS + kc*8;
    loff[j] = p*8;
  }
  const unsigned short* Abase = Wbf + (size_t)Mbase * CHANNELS;
  const unsigned short* Bbase = Sbf + ((size_t)bb*SPATIAL + Nbase) * CHANNELS;

  f32x4 acc[4][4];
  #pragma unroll
  for (int i=0;i<4;++i)
    #pragma unroll
    for (int j=0;j<4;++j){
      f32x4 z = {0.f,0.f,0.f,0.f};
      acc[i][j] = z;
    }

  // fragment read bases (shorts): addr(row, kc) = row*64 + (kc^(row&7))*8
  // row = w?*64 + i*16 + (lane&15)  ->  row&7 == lane&7
  // kc  = ks*4 + (lane>>4)
  const int r7 = lane & 7;
  const int rbA = (wm*64 + (lane & 15))*64;
  const int rbB = (wn*64 + (lane & 15))*64;
  const int x0 = (((lane >> 4)    ) ^ r7) * 8;
  const int x1 = (((lane >> 4) + 4) ^ r7) * 8;

  for (int kt = 0; kt < 16; ++kt){
    const int ko = kt * 64;
    #pragma unroll
    for (int j = 0; j < 4; ++j){
      async_load16(Abase + voff[j] + ko, lA + loff[j]);
      async_load16(Bbase + voff[j] + ko, lB + loff[j]);
    }
    __syncthreads();
    #pragma unroll
    for (int ks = 0; ks < 2; ++ks){
      const int xo = ks ? x1 : x0;
      s16x8 af[4], bv[4];
      #pragma unroll
      for (int i=0;i<4;++i) af[i] = *(const s16x8*)&lA[rbA + i*1024 + xo];
      #pragma unroll
      for (int j=0;j<4;++j) bv[j] = *(const s16x8*)&lB[rbB + j*1024 + xo];
      #pragma unroll
      for (int i=0;i<4;++i)
        #pragma unroll
        for (int j=0;j<4;++j)
          acc[i][j] = __builtin_amdgcn_mfma_f32_16x16x32_bf16(af[i], bv[j], acc[i][j], 0, 0, 0);
    }
    __syncthreads();
  }

  // C/D layout: col = lane&15, row = (lane>>4)*4 + reg
  float* outb = out + (size_t)b * CHANNELS * SPATIAL;
  const int col  = Nbase + wn*64 + (lane & 15);
  const int row0 = Mbase + wm*64 + ((lane >> 4) << 2);
  #pragma unroll
  for (int i=0;i<4;++i)
    #pragma unroll
    for (int j=0;j<4;++j)
      #pragma unroll
      for (int r=0;r<4;++r)
        outb[(size_t)(row0 + i*16 + r) * SPATIAL + (col + j*16)] = acc[i][j][r];
}

// ---------------------------------------------- emergency small-ws path ----
__global__ void sy_fallback(const float* __restrict__ weight, const float4* __restrict__ params,
                            float* __restrict__ out){
  extern __shared__ float S[];   // 32*1024 floats = 128 KB
  int b  = blockIdx.x >> 7;
  int m0 = (blockIdx.x & 127) * 32;
  int t  = threadIdx.x;
  {
    int c0 = t*4;
    float4 P0 = params[b*CHANNELS+c0+0], P1 = params[b*CHANNELS+c0+1];
    float4 P2 = params[b*CHANNELS+c0+2], P3 = params[b*CHANNELS+c0+3];
    int h = m0 >> 6;
    float v = (h + 0.5f)*(1.0f/64.0f) - 0.5f;
    float a0 = v*P0.y+P0.z, a1 = v*P1.y+P1.z, a2 = v*P2.y+P2.z, a3 = v*P3.y+P3.z;
    for (int im = 0; im < 32; ++im){
      int wv = (m0+im) & 63;
      float u = (wv+0.5f)*(1.0f/64.0f) - 0.5f;
      float* row = S + im*CHANNELS + c0;
      row[0] = sin2pi(u*P0.x+a0)*P0.w;
      row[1] = sin2pi(u*P1.x+a1)*P1.w;
      row[2] = sin2pi(u*P2.x+a2)*P2.w;
      row[3] = sin2pi(u*P3.x+a3)*P3.w;
    }
  }
  __syncthreads();
  for (int oi = t; oi < 32*1024; oi += 256){
    int k = oi >> 5, im = oi & 31;
    const float4* wr = (const float4*)(weight + (size_t)k*CHANNELS);
    const float4* sr = (const float4*)(S + im*CHANNELS);
    float sum = 0.f;
    for (int c4 = 0; c4 < CHANNELS/4; ++c4){
      float4 a = wr[c4], s4 = sr[c4];
      sum += a.x*s4.x + a.y*s4.y + a.z*s4.z + a.w*s4.w;
    }
    out[((size_t)b*CHANNELS + k)*SPATIAL + m0 + im] = sum * 0.03125f;
  }
}

extern "C" void kernel_launch(void* const* d_in, const int* in_sizes, int n_in,
                              void* d_out, int out_size, void* d_ws, size_t ws_size,
                              hipStream_t stream){
  const float* w        = (const float*)d_in[0];
  const float* freqs    = (const float*)d_in[1];
  const float* phases   = (const float*)d_in[2];
  const float* weight   = (const float*)d_in[3];
  const float* affine_w = (const float*)d_in[4];
  const float* affine_b = (const float*)d_in[5];
  float* out = (float*)d_out;

  char* ws = (char*)d_ws;
  float4* params = (float4*)ws;                       // 256 KB
  const size_t off_w = 262144;                        // Wbf: 2 MiB
  const size_t off_s = off_w + 2097152;               // Sbf: up to 128 MiB
  unsigned short* Wbf = (unsigned short*)(ws + off_w);
  unsigned short* Sbf = (unsigned short*)(ws + off_s);
  const size_t per_batch = (size_t)SPATIAL * CHANNELS * 2;  // 8 MiB

  sy_setup<<<NB, 256, 0, stream>>>(w, freqs, phases, affine_w, affine_b, params);

  int G = 0;
  if (ws_size >= off_s + per_batch){
    size_t avail = (ws_size - off_s) / per_batch;
    G = avail >= (size_t)NB ? NB : (int)avail;
  }
  if (G == 0){
    sy_fallback<<<NB*128, 256, 32*1024*4, stream>>>(weight, params, out);
    return;
  }
  sy_cvtw<<<1024, 256, 0, stream>>>(weight, Wbf);
  for (int b0 = 0; b0 < NB; b0 += G){
    int g = (NB - b0) < G ? (NB - b0) : G;
    sy_genS<<<g*128, 256, 0, stream>>>(params, Sbf, b0);
    dim3 grid(32, 8, g);
    sy_gemm<<<grid, 256, 0, stream>>>(Wbf, Sbf, out, b0);
  }
}